// Round 1
// baseline (223.220 us; speedup 1.0000x reference)
//
#include <hip/hip_runtime.h>
#include <cfloat>
#include <climits>

#define ROWS    1024
#define VOCABSZ 128000
#define NBEAMS  16
#define NBATCH  64
#define CURLEN  8
#define KTOP    16
#define WPB     4                    // waves per block (kernel 1)
#define SEGSZ   (VOCABSZ / WPB)      // 32000 elements per wave segment
#define NITER   (SEGSZ / 256)        // 125 iterations of 64 lanes x float4
#define CBUF    528                  // candidate buffer capacity per wave
#define FLUSHT  (CBUF - 256)         // flush threshold: room for one full iter

// ---------------------------------------------------------------------------
// Kernel 1: one block per row; each wave owns a contiguous 32000-elem segment.
// Single pass: online (max, sumexp) for log-softmax constant + filtered
// top-16 candidate selection on raw logits (score is monotone in raw logit
// within a row). Candidates + (M,S) go to workspace.
// ---------------------------------------------------------------------------
__global__ __launch_bounds__(256) void k1_scan(const float* __restrict__ logits,
                                               float* __restrict__ wsM,
                                               float* __restrict__ wsS,
                                               float* __restrict__ wsV,
                                               int* __restrict__ wsI) {
    __shared__ float bufv[WPB][CBUF];
    __shared__ int   bufi[WPB][CBUF];
    __shared__ float redM[WPB], redS[WPB];

    const int row  = blockIdx.x;
    const int w    = threadIdx.x >> 6;
    const int lane = threadIdx.x & 63;
    const float* seg = logits + (size_t)row * VOCABSZ + (size_t)w * SEGSZ;

    float m = -FLT_MAX, s = 0.f;     // online logsumexp state
    float thr = -FLT_MAX;            // wave-uniform candidate threshold
    int   cnt = 0;                   // wave-uniform buffer count
    float kv = -FLT_MAX; int ki = 0; // lane r holds r-th winner after flush

    // wave-local flush: keep top-16 of buffer, raise threshold
    auto flush = [&]() {
        float fkv = -FLT_MAX; int fki = 0;
        for (int r = 0; r < KTOP; r++) {
            float bv = -FLT_MAX; int bi = INT_MAX; int bp = -1;
            for (int e = lane; e < cnt; e += 64) {
                float v  = bufv[w][e];
                int   ii = bufi[w][e];
                if (v > bv || (v == bv && ii < bi)) { bv = v; bi = ii; bp = e; }
            }
            for (int o = 32; o > 0; o >>= 1) {
                float ov  = __shfl_xor(bv, o);
                int   oi  = __shfl_xor(bi, o);
                int   op  = __shfl_xor(bp, o);
                if (ov > bv || (ov == bv && oi < bi)) { bv = ov; bi = oi; bp = op; }
            }
            if (lane == r) { fkv = bv; fki = bi; }
            if (lane == 0) bufv[w][bp] = -FLT_MAX;   // mark consumed
            thr = bv;                                 // after r=15: 16th value
        }
        if (lane < KTOP) { bufv[w][lane] = fkv; bufi[w][lane] = fki; }
        kv = fkv; ki = fki;
        cnt = KTOP;
    };

    for (int i = 0; i < NITER; i++) {
        const float4 x4 = *reinterpret_cast<const float4*>(seg + i * 256 + lane * 4);

        // --- online logsumexp (per-4 then combine) ---
        float m4 = fmaxf(fmaxf(x4.x, x4.y), fmaxf(x4.z, x4.w));
        float s4 = expf(x4.x - m4) + expf(x4.y - m4) + expf(x4.z - m4) + expf(x4.w - m4);
        float nm = fmaxf(m, m4);
        s = s * expf(m - nm) + s4 * expf(m4 - nm);
        m = nm;

        // --- filtered candidate append (ballot compaction) ---
        const int vbase = w * SEGSZ + i * 256 + lane * 4;
        float xs[4] = {x4.x, x4.y, x4.z, x4.w};
        #pragma unroll
        for (int j = 0; j < 4; j++) {
            const float x = xs[j];
            const bool pred = x > thr;
            const unsigned long long mask = __ballot(pred);
            if (mask) {
                const int pos = cnt + __popcll(mask & ((1ull << lane) - 1ull));
                if (pred) { bufv[w][pos] = x; bufi[w][pos] = vbase + j; }
                cnt += __popcll(mask);
            }
        }
        if (cnt > FLUSHT) flush();
    }
    if (cnt > KTOP) flush();

    // wave reduce (m, s)
    for (int o = 32; o > 0; o >>= 1) {
        float om = __shfl_xor(m, o);
        float os = __shfl_xor(s, o);
        float nm = fmaxf(m, om);
        s = s * expf(m - nm) + os * expf(om - nm);
        m = nm;
    }
    if (lane == 0) { redM[w] = m; redS[w] = s; }
    __syncthreads();
    if (threadIdx.x == 0) {
        float M = redM[0];
        for (int i = 1; i < WPB; i++) M = fmaxf(M, redM[i]);
        float S = 0.f;
        for (int i = 0; i < WPB; i++) S += redS[i] * expf(redM[i] - M);
        wsM[row] = M;
        wsS[row] = S;
    }
    // each wave writes its own top-16 (lane r holds r-th winner)
    if (lane < KTOP) {
        wsV[(size_t)row * 64 + w * KTOP + lane] = kv;
        wsI[(size_t)row * 64 + w * KTOP + lane] = ki;
    }
}

// ---------------------------------------------------------------------------
// Kernel 2: one wave per batch. 16 rows x 64 candidates = 1024 candidates.
// Exact reference scoring ((x-M)-logS)+bs, top-16 with jax tie-break
// (score desc, flat idx beam*V+v asc), then emit outputs as float32.
// ---------------------------------------------------------------------------
__global__ __launch_bounds__(64) void k2_select(const float* __restrict__ wsM,
                                                const float* __restrict__ wsS,
                                                const float* __restrict__ wsV,
                                                const int* __restrict__ wsI,
                                                const float* __restrict__ beam_scores,
                                                const int* __restrict__ dec_ids,
                                                const int* __restrict__ beam_idx_offset,
                                                float* __restrict__ out) {
    const int batch = blockIdx.x;
    const int lane  = threadIdx.x;   // 0..63

    __shared__ float Ms[NBEAMS], LSs[NBEAMS], BSs[NBEAMS];
    if (lane < NBEAMS) {
        const int row = batch * NBEAMS + lane;
        Ms[lane]  = wsM[row];
        LSs[lane] = logf(wsS[row]);
        BSs[lane] = beam_scores[row];
    }
    __syncthreads();

    // candidate (p, lane): row p within batch, slot lane
    float sc[16]; int cb[16];
    #pragma unroll
    for (int p = 0; p < 16; p++) {
        const size_t base = (size_t)(batch * NBEAMS + p) * 64 + lane;
        const float v = wsV[base];
        const int idx = wsI[base];
        sc[p] = ((v - Ms[p]) - LSs[p]) + BSs[p];   // reference rounding order
        cb[p] = p * VOCABSZ + idx;
    }

    unsigned int selmask = 0;
    float fs = 0.f; int fc = 0;       // lane r keeps r-th winner
    for (int r = 0; r < KTOP; r++) {
        float bv = -FLT_MAX; int bi = INT_MAX; int bslot = -1;
        #pragma unroll
        for (int p = 0; p < 16; p++) {
            const bool avail = !((selmask >> p) & 1u);
            if (avail && (sc[p] > bv || (sc[p] == bv && cb[p] < bi))) {
                bv = sc[p]; bi = cb[p]; bslot = p;
            }
        }
        int bl = lane;
        for (int o = 32; o > 0; o >>= 1) {
            float ov  = __shfl_xor(bv, o);
            int   oi  = __shfl_xor(bi, o);
            int   obl = __shfl_xor(bl, o);
            int   obs = __shfl_xor(bslot, o);
            if (ov > bv || (ov == bv && oi < bi)) { bv = ov; bi = oi; bl = obl; bslot = obs; }
        }
        if (lane == bl) selmask |= (1u << bslot);
        if (lane == r) { fs = bv; fc = bi; }
    }

    if (lane < NBEAMS) {
        const int out_row = batch * NBEAMS + lane;
        const int beam  = fc / VOCABSZ;
        const int token = fc - beam * VOCABSZ;
        float* out0 = out;                          // (1024, 9) ids as f32
        float* out1 = out + ROWS * (CURLEN + 1);    // (1024,) scores
        out1[out_row] = fs;
        const int src = beam + beam_idx_offset[out_row];
        #pragma unroll
        for (int j = 0; j < CURLEN; j++)
            out0[out_row * (CURLEN + 1) + j] = (float)dec_ids[src * CURLEN + j];
        out0[out_row * (CURLEN + 1) + CURLEN] = (float)token;
    }
}

extern "C" void kernel_launch(void* const* d_in, const int* in_sizes, int n_in,
                              void* d_out, int out_size, void* d_ws, size_t ws_size,
                              hipStream_t stream) {
    const float* logits = (const float*)d_in[0];
    const int*   dec    = (const int*)d_in[1];
    const float* bscore = (const float*)d_in[2];
    const int*   bio    = (const int*)d_in[3];

    float* ws  = (float*)d_ws;
    float* wsM = ws;                       // 1024
    float* wsS = ws + ROWS;                // 1024
    float* wsV = ws + 2 * ROWS;            // 1024*64
    int*   wsI = (int*)(ws + 2 * ROWS + ROWS * 64);

    k1_scan<<<ROWS, 256, 0, stream>>>(logits, wsM, wsS, wsV, wsI);
    k2_select<<<NBATCH, 64, 0, stream>>>(wsM, wsS, wsV, wsI, bscore, dec, bio,
                                         (float*)d_out);
}

// Round 2
// 179.690 us; speedup vs baseline: 1.2423x; 1.2423x over previous
//
#include <hip/hip_runtime.h>
#include <cfloat>
#include <climits>

#define ROWS    1024
#define VOCABSZ 128000
#define NBEAMS  16
#define NBATCH  64
#define CURLEN  8
#define KTOP    16
#define WPB     4                    // waves per block (kernel 1)
#define SEGSZ   (VOCABSZ / WPB)      // 32000 elements per wave segment
#define NITER   (SEGSZ / 256)        // 125 iterations of 64 lanes x float4
#define CBUF    528                  // candidate buffer capacity per wave
#define FLUSHT  (CBUF - 260)         // flush threshold: room for one full iter
#define LOG2E   1.4426950408889634f
#define LN2     0.6931471805599453f

#if __has_builtin(__builtin_amdgcn_exp2f)
#define EXP2(x) __builtin_amdgcn_exp2f(x)
#else
#define EXP2(x) exp2f(x)
#endif

// ---------------------------------------------------------------------------
// Kernel 1: one block per row; each wave owns a contiguous 32000-elem segment.
// Single pass in base-2 domain (y = x*log2e): online (max, sum 2^(y-max))
// + filtered top-16 candidate selection (score monotone in y within a row).
// Common path per 4 elems: 4 mul, 3 max, 5 exp2, 4 sub, adds, 1 wave-any.
// Candidate append + flush is a cold branch after the first flush.
// ---------------------------------------------------------------------------
__global__ __launch_bounds__(256) void k1_scan(const float* __restrict__ logits,
                                               float* __restrict__ wsM,
                                               float* __restrict__ wsS,
                                               float* __restrict__ wsV,
                                               int* __restrict__ wsI) {
    __shared__ float bufv[WPB][CBUF];
    __shared__ int   bufi[WPB][CBUF];
    __shared__ float redM[WPB], redS[WPB];

    const int row  = blockIdx.x;
    const int w    = threadIdx.x >> 6;
    const int lane = threadIdx.x & 63;
    const float4* seg4 = reinterpret_cast<const float4*>(
        logits + (size_t)row * VOCABSZ + (size_t)w * SEGSZ);

    float m = -FLT_MAX, s = 0.f;     // base-2 online logsumexp state
    float thr = -FLT_MAX;            // wave-uniform candidate threshold (y-domain)
    int   cnt = 0;                   // wave-uniform buffer count
    float kv = -FLT_MAX; int ki = 0; // lane r holds r-th winner after flush

    // wave-local flush: keep top-16 of buffer, raise threshold
    auto flush = [&]() {
        float fkv = -FLT_MAX; int fki = 0;
        for (int r = 0; r < KTOP; r++) {
            float bv = -FLT_MAX; int bi = INT_MAX; int bp = -1;
            for (int e = lane; e < cnt; e += 64) {
                float v  = bufv[w][e];
                int   ii = bufi[w][e];
                if (v > bv || (v == bv && ii < bi)) { bv = v; bi = ii; bp = e; }
            }
            for (int o = 32; o > 0; o >>= 1) {
                float ov  = __shfl_xor(bv, o);
                int   oi  = __shfl_xor(bi, o);
                int   op  = __shfl_xor(bp, o);
                if (ov > bv || (ov == bv && oi < bi)) { bv = ov; bi = oi; bp = op; }
            }
            if (lane == r) { fkv = bv; fki = bi; }
            if (lane == 0) bufv[w][bp] = -FLT_MAX;   // mark consumed
            thr = bv;                                 // after r=15: 16th value
        }
        if (lane < KTOP) { bufv[w][lane] = fkv; bufi[w][lane] = fki; }
        kv = fkv; ki = fki;
        cnt = KTOP;
    };

    // depth-2 software prefetch
    float4 A = seg4[lane];
    float4 B = seg4[64 + lane];

    for (int i = 0; i < NITER; i++) {
        float4 C = A;
        if (i + 2 < NITER) C = seg4[(i + 2) * 64 + lane];

        const float y0 = A.x * LOG2E, y1 = A.y * LOG2E;
        const float y2 = A.z * LOG2E, y3 = A.w * LOG2E;
        const float m4 = fmaxf(fmaxf(y0, y1), fmaxf(y2, y3));
        const float nm = fmaxf(m, m4);
        s = s * EXP2(m - nm)
          + ((EXP2(y0 - nm) + EXP2(y1 - nm)) + (EXP2(y2 - nm) + EXP2(y3 - nm)));
        m = nm;

        // cold path: candidate append (rare after first flush)
        if (__any(m4 > thr)) {
            const int vbase = w * SEGSZ + i * 256 + lane * 4;
            float ys[4] = {y0, y1, y2, y3};
            #pragma unroll
            for (int j = 0; j < 4; j++) {
                const bool pred = ys[j] > thr;
                const unsigned long long mask = __ballot(pred);
                if (mask) {
                    const int pos = cnt + __popcll(mask & ((1ull << lane) - 1ull));
                    if (pred) { bufv[w][pos] = ys[j]; bufi[w][pos] = vbase + j; }
                    cnt += __popcll(mask);
                }
            }
            if (cnt > FLUSHT) flush();
        }
        A = B; B = C;
    }
    if (cnt > KTOP) flush();

    // wave reduce (m, s) in base-2
    for (int o = 32; o > 0; o >>= 1) {
        float om = __shfl_xor(m, o);
        float os = __shfl_xor(s, o);
        float nm = fmaxf(m, om);
        s = s * EXP2(m - nm) + os * EXP2(om - nm);
        m = nm;
    }
    if (lane == 0) { redM[w] = m; redS[w] = s; }
    __syncthreads();
    if (threadIdx.x == 0) {
        float M = redM[0];
        for (int i = 1; i < WPB; i++) M = fmaxf(M, redM[i]);
        float S = 0.f;
        for (int i = 0; i < WPB; i++) S += redS[i] * EXP2(redM[i] - M);
        wsM[row] = M;                // y-domain max
        wsS[row] = S;                // sum 2^(y - M)
    }
    // each wave writes its own top-16 (lane r holds r-th winner, y-domain)
    if (lane < KTOP) {
        wsV[(size_t)row * 64 + w * KTOP + lane] = kv;
        wsI[(size_t)row * 64 + w * KTOP + lane] = ki;
    }
}

// ---------------------------------------------------------------------------
// Kernel 2: one wave per batch. 16 rows x 64 candidates = 1024 candidates.
// Score in base-2 domain: sc = ln2*((y - M2) - log2(S)) + bs, top-16 with
// jax tie-break (score desc, flat idx beam*V+v asc), emit outputs as f32.
// ---------------------------------------------------------------------------
__global__ __launch_bounds__(64) void k2_select(const float* __restrict__ wsM,
                                                const float* __restrict__ wsS,
                                                const float* __restrict__ wsV,
                                                const int* __restrict__ wsI,
                                                const float* __restrict__ beam_scores,
                                                const int* __restrict__ dec_ids,
                                                const int* __restrict__ beam_idx_offset,
                                                float* __restrict__ out) {
    const int batch = blockIdx.x;
    const int lane  = threadIdx.x;   // 0..63

    __shared__ float Ms[NBEAMS], LSs[NBEAMS], BSs[NBEAMS];
    if (lane < NBEAMS) {
        const int row = batch * NBEAMS + lane;
        Ms[lane]  = wsM[row];
        LSs[lane] = log2f(wsS[row]);
        BSs[lane] = beam_scores[row];
    }
    __syncthreads();

    // candidate (p, lane): row p within batch, slot lane
    float sc[16]; int cb[16];
    #pragma unroll
    for (int p = 0; p < 16; p++) {
        const size_t base = (size_t)(batch * NBEAMS + p) * 64 + lane;
        const float v = wsV[base];               // y-domain
        const int idx = wsI[base];
        sc[p] = ((v - Ms[p]) - LSs[p]) * LN2 + BSs[p];
        cb[p] = p * VOCABSZ + idx;
    }

    unsigned int selmask = 0;
    float fs = 0.f; int fc = 0;       // lane r keeps r-th winner
    for (int r = 0; r < KTOP; r++) {
        float bv = -FLT_MAX; int bi = INT_MAX; int bslot = -1;
        #pragma unroll
        for (int p = 0; p < 16; p++) {
            const bool avail = !((selmask >> p) & 1u);
            if (avail && (sc[p] > bv || (sc[p] == bv && cb[p] < bi))) {
                bv = sc[p]; bi = cb[p]; bslot = p;
            }
        }
        int bl = lane;
        for (int o = 32; o > 0; o >>= 1) {
            float ov  = __shfl_xor(bv, o);
            int   oi  = __shfl_xor(bi, o);
            int   obl = __shfl_xor(bl, o);
            int   obs = __shfl_xor(bslot, o);
            if (ov > bv || (ov == bv && oi < bi)) { bv = ov; bi = oi; bl = obl; bslot = obs; }
        }
        if (lane == bl) selmask |= (1u << bslot);
        if (lane == r) { fs = bv; fc = bi; }
    }

    if (lane < NBEAMS) {
        const int out_row = batch * NBEAMS + lane;
        const int beam  = fc / VOCABSZ;
        const int token = fc - beam * VOCABSZ;
        float* out0 = out;                          // (1024, 9) ids as f32
        float* out1 = out + ROWS * (CURLEN + 1);    // (1024,) scores
        out1[out_row] = fs;
        const int src = beam + beam_idx_offset[out_row];
        #pragma unroll
        for (int j = 0; j < CURLEN; j++)
            out0[out_row * (CURLEN + 1) + j] = (float)dec_ids[src * CURLEN + j];
        out0[out_row * (CURLEN + 1) + CURLEN] = (float)token;
    }
}

extern "C" void kernel_launch(void* const* d_in, const int* in_sizes, int n_in,
                              void* d_out, int out_size, void* d_ws, size_t ws_size,
                              hipStream_t stream) {
    const float* logits = (const float*)d_in[0];
    const int*   dec    = (const int*)d_in[1];
    const float* bscore = (const float*)d_in[2];
    const int*   bio    = (const int*)d_in[3];

    float* ws  = (float*)d_ws;
    float* wsM = ws;                       // 1024
    float* wsS = ws + ROWS;                // 1024
    float* wsV = ws + 2 * ROWS;            // 1024*64
    int*   wsI = (int*)(ws + 2 * ROWS + ROWS * 64);

    k1_scan<<<ROWS, 256, 0, stream>>>(logits, wsM, wsS, wsV, wsI);
    k2_select<<<NBATCH, 64, 0, stream>>>(wsM, wsS, wsV, wsI, bscore, dec, bio,
                                         (float*)d_out);
}